// Round 4
// baseline (237.094 us; speedup 1.0000x reference)
//
#include <hip/hip_runtime.h>

typedef unsigned short u16;
typedef __bf16 bf16x8 __attribute__((ext_vector_type(8)));
typedef float f32x4 __attribute__((ext_vector_type(4)));
typedef unsigned short u16x8 __attribute__((ext_vector_type(8)));

#define F_FACES 65536
#define N_FACES 131072
#define C_CH 128
// ws layout (bytes):
//   [0,256)        zeropage (zeros; masked-gather target)
//   [256,3328)     W2 folded fp32  [b][o][i]  (2*3*128 floats)
//   [3328,4352)    styles1 fp32    [b][i]     (256 floats)
//   [4352,594176)  W1 folded bf16  [b][k][o][i] (2*9*128*128)
//   [594176, +16777216) const bf16 copy [F][C]
#define WS_W2F 256
#define WS_S1 3328
#define WS_W1 4352
#define WS_CONST 594176
#define XELEMS 16777216  // N_FACES*128

__device__ inline u16 f2bf(float f) {
    unsigned u = __builtin_bit_cast(unsigned, f);
    unsigned r = (u + 0x7fffu + ((u >> 16) & 1u)) >> 16;
    return (u16)r;
}

__device__ inline void gl_lds16(const void* g, void* l) {
    __builtin_amdgcn_global_load_lds(
        (const __attribute__((address_space(1))) void*)g,
        (__attribute__((address_space(3))) void*)l, 16, 0, 0);
}

// ---------------- kernel 0a: styles + W2 fold + zeropage ----------------
__global__ __launch_bounds__(256) void k0_styles(
    const float* __restrict__ wsv, const float* __restrict__ a1W, const float* __restrict__ a1b,
    const float* __restrict__ a2W, const float* __restrict__ a2b, const float* __restrict__ w2,
    unsigned char* __restrict__ wsb)
{
    __shared__ float s2s[256];
    int t = threadIdx.x;
    int b = t >> 7, o = t & 127;
    const float* w0r = wsv + (b * 2 + 0) * 512;
    const float* w1r = wsv + (b * 2 + 1) * 512;
    const float* r1 = a1W + o * 512;
    const float* r2 = a2W + o * 512;
    float s1 = 0.f, s2 = 0.f;
    for (int j = 0; j < 512; j += 4) {
        float4 x0 = *(const float4*)(w0r + j);
        float4 x1 = *(const float4*)(w1r + j);
        float4 y1 = *(const float4*)(r1 + j);
        float4 y2 = *(const float4*)(r2 + j);
        s1 += x0.x * y1.x + x0.y * y1.y + x0.z * y1.z + x0.w * y1.w;
        s2 += x1.x * y2.x + x1.y * y2.y + x1.z * y2.z + x1.w * y2.w;
    }
    const float g512 = 0.04419417382415922f;   // 1/sqrt(512)
    const float g128 = 0.08838834764831845f;   // 1/sqrt(128)
    float st1 = s1 * g512 + a1b[o];
    float st2 = (s2 * g512 + a2b[o]) * g128;
    float* wsf = (float*)wsb;
    wsf[WS_S1 / 4 + t] = st1;
    s2s[t] = st2;
    if (t < 64) wsf[t] = 0.f;  // zeropage
    __syncthreads();
#pragma unroll
    for (int r = 0; r < 3; ++r) {
        int id = t + r * 256;  // < 768
        int b2 = id / 384;
        int rem = id - b2 * 384;
        int o2 = rem >> 7;
        int i = rem & 127;
        wsf[WS_W2F / 4 + id] = w2[o2 * 128 + i] * s2s[b2 * 128 + i];
    }
}

// ---------------- kernel 0b: demod + fold W1 (bf16, [b][k][o][i]) ----------------
__global__ __launch_bounds__(64) void k0b_fold(
    const float* __restrict__ w1g, const float* __restrict__ s1base, u16* __restrict__ w1out)
{
    int bo = blockIdx.x;
    int b = bo >> 7, o = bo & 127;
    int l = threadIdx.x;
    const float* s1 = s1base + b * 128;
    float sum = 0.f;
    for (int e = l; e < 1152; e += 64) {
        int i = e / 9;
        float w = w1g[o * 1152 + e] * s1[i];
        sum += w * w;
    }
#pragma unroll
    for (int d = 1; d < 64; d <<= 1) sum += __shfl_xor(sum, d);
    float dm = rsqrtf(sum + 1e-8f);
    int i0 = l * 2;
    float sa = s1[i0] * dm, sb = s1[i0 + 1] * dm;
#pragma unroll
    for (int k = 0; k < 9; ++k) {
        float v0 = w1g[(o * 128 + i0) * 9 + k] * sa;
        float v1 = w1g[(o * 128 + i0 + 1) * 9 + k] * sb;
        unsigned pack = (unsigned)f2bf(v0) | ((unsigned)f2bf(v1) << 16);
        *(unsigned*)&w1out[(size_t)(((b * 9 + k) * 128 + o) * 128) + i0] = pack;
    }
}

// ---------------- kernel 0c: const fp32 -> bf16 copy in ws ----------------
__global__ __launch_bounds__(256) void k_cvt(
    const float* __restrict__ src, u16* __restrict__ dst)
{
    int t = blockIdx.x * 256 + threadIdx.x;
    int base = t * 8;  // 4096 blocks * 256 thr * 8 = 8388608
    float4 a = *(const float4*)(src + base);
    float4 c = *(const float4*)(src + base + 4);
    u16x8 p;
    p[0] = f2bf(a.x); p[1] = f2bf(a.y); p[2] = f2bf(a.z); p[3] = f2bf(a.w);
    p[4] = f2bf(c.x); p[5] = f2bf(c.y); p[6] = f2bf(c.z); p[7] = f2bf(c.w);
    *(u16x8*)(dst + base) = p;
}

// ---------------- kernel 1: gathered GEMM conv1 + fused epilogue ----------------
__global__ __launch_bounds__(256, 2) void k1_conv(
    const int* __restrict__ neigh, const int* __restrict__ ispad,
    const float* __restrict__ noise_c, const float* __restrict__ nstr,
    const float* __restrict__ bias1, const unsigned char* __restrict__ wsb,
    float* __restrict__ out)
{
    __shared__ u16 As[128 * 128];  // 32KB, 128 faces x 128ch, 16B-chunk XOR swizzled
    __shared__ u16 Bs[128 * 128];  // 32KB, 128 o x 128 k, 16B-chunk XOR swizzled

    int tid = threadIdx.x;
    int wv = tid >> 6, lane = tid & 63;
    int quad = lane >> 4, l15 = lane & 15;
    int f0 = blockIdx.x * 128;
    int b = f0 >> 16;
    const u16* cst = (const u16*)(wsb + WS_CONST);
    const u16* w1ws = (const u16*)(wsb + WS_W1) + (size_t)b * 147456;  // 9*128*128
    const char* zp = (const char*)wsb;

    // per-thread fixed staging assignment: 8 issues per operand.
    // physical LDS chunk cid holds global chunk (slot ^ (row&15)) of row (cid>>4)
    // for BOTH A and B (write-side swizzle; read side XORs identically).
    int nidx[8];   // neigh row base (A)
    int cg16[8];   // swizzled within-row chunk byte offset (A and B share formula)
    int brow[8];   // B row byte base
    int ldso[8];   // wave-uniform LDS byte base per issue
#pragma unroll
    for (int r = 0; r < 8; ++r) {
        int cid = ((wv * 8 + r) << 6) + lane;
        int row = cid >> 4;
        int slot = cid & 15;
        nidx[r] = (f0 + row) * 9;
        cg16[r] = ((slot ^ (row & 15)) << 4);
        brow[r] = row << 8;  // row * 256 bytes
        ldso[r] = (wv * 8 + r) << 10;
    }

    f32x4 acc[4][4] = {};
    int wm = wv & 1, wn = wv >> 1;

    for (int k = 0; k < 9; ++k) {
        __syncthreads();
        // stage A (gather, masked -> zeropage), swizzled write
#pragma unroll
        for (int r = 0; r < 8; ++r) {
            int idx = neigh[nidx[r] + k];
            bool valid = (ispad[nidx[r] + k] == 0) && ((unsigned)idx < 131072u);
            const char* src = valid ? ((const char*)(cst + ((size_t)(idx & 65535) << 7))) : zp;
            gl_lds16(src + cg16[r], (char*)As + ldso[r]);
        }
        // stage B (from pre-folded ws), SAME swizzled write as A
        const char* bsrc = (const char*)(w1ws + k * 16384);
#pragma unroll
        for (int r = 0; r < 8; ++r) {
            gl_lds16(bsrc + brow[r] + cg16[r], (char*)Bs + ldso[r]);
        }
        __syncthreads();
#pragma unroll
        for (int s = 0; s < 4; ++s) {
            bf16x8 af[4], bfr[4];
#pragma unroll
            for (int mt = 0; mt < 4; ++mt) {
                int face = wm * 64 + mt * 16 + l15;
                int chunk = (s * 4 + quad) ^ (face & 15);
                af[mt] = *reinterpret_cast<const bf16x8*>(&As[face * 128 + chunk * 8]);
            }
#pragma unroll
            for (int nt = 0; nt < 4; ++nt) {
                int o = wn * 64 + nt * 16 + l15;
                int chunk = (s * 4 + quad) ^ (o & 15);
                bfr[nt] = *reinterpret_cast<const bf16x8*>(&Bs[o * 128 + chunk * 8]);
            }
#pragma unroll
            for (int mt = 0; mt < 4; ++mt)
#pragma unroll
                for (int nt = 0; nt < 4; ++nt)
                    acc[mt][nt] = __builtin_amdgcn_mfma_f32_16x16x32_bf16(
                        af[mt], bfr[nt], acc[mt][nt], 0, 0, 0);
        }
    }

    // epilogue: + noise + bias1, lrelu(0.2)*sqrt(2), clip +-256, fp32 store
    float ns = nstr[0];
    float b1v[4];
#pragma unroll
    for (int nt = 0; nt < 4; ++nt) b1v[nt] = bias1[wn * 64 + nt * 16 + l15];
#pragma unroll
    for (int mt = 0; mt < 4; ++mt) {
#pragma unroll
        for (int r = 0; r < 4; ++r) {
            int face = f0 + wm * 64 + mt * 16 + quad * 4 + r;
            float nz = noise_c[face & 65535] * ns;
#pragma unroll
            for (int nt = 0; nt < 4; ++nt) {
                float v = acc[mt][nt][r] + nz + b1v[nt];
                v = (v > 0.f) ? v : 0.2f * v;
                v *= 1.41421356f;
                v = fminf(fmaxf(v, -256.f), 256.f);
                out[(size_t)face * 128 + wn * 64 + nt * 16 + l15] = v;
            }
        }
    }
}

// ---------------- kernel 2: conv2 (k=1 gather) + bias + clip ----------------
__global__ __launch_bounds__(256) void k2_img(
    const int* __restrict__ neigh, const int* __restrict__ ispad,
    const float* __restrict__ w2f, const float* __restrict__ bias2,
    const float* __restrict__ xbuf, float* __restrict__ imgout)
{
    int tid = threadIdx.x;
    int wv = tid >> 6, lane = tid & 63;
    int g = lane >> 4, sub = lane & 15;
    int face = blockIdx.x * 16 + wv * 4 + g;
    int b = face >> 16;
    float w[3][8];
#pragma unroll
    for (int o = 0; o < 3; ++o)
#pragma unroll
        for (int j = 0; j < 8; ++j) w[o][j] = w2f[(b * 3 + o) * 128 + sub * 8 + j];
    int idx = neigh[face * 9];
    bool valid = (ispad[face * 9] == 0) && ((unsigned)idx < 131072u);
    float a0 = 0.f, a1 = 0.f, a2 = 0.f;
    if (valid) {
        float4 d0 = *(const float4*)(xbuf + (size_t)idx * 128 + sub * 8);
        float4 d1 = *(const float4*)(xbuf + (size_t)idx * 128 + sub * 8 + 4);
        float f[8] = {d0.x, d0.y, d0.z, d0.w, d1.x, d1.y, d1.z, d1.w};
#pragma unroll
        for (int j = 0; j < 8; ++j) {
            a0 += f[j] * w[0][j];
            a1 += f[j] * w[1][j];
            a2 += f[j] * w[2][j];
        }
    }
#pragma unroll
    for (int d = 1; d < 16; d <<= 1) {
        a0 += __shfl_xor(a0, d);
        a1 += __shfl_xor(a1, d);
        a2 += __shfl_xor(a2, d);
    }
    if (sub < 3) {
        float v = (sub == 0) ? a0 : (sub == 1) ? a1 : a2;
        v += bias2[sub];
        v = fminf(fmaxf(v, -256.f), 256.f);
        imgout[face * 3 + sub] = v;
    }
}

extern "C" void kernel_launch(void* const* d_in, const int* in_sizes, int n_in,
                              void* d_out, int out_size, void* d_ws, size_t ws_size,
                              hipStream_t stream) {
    const int* neigh = (const int*)d_in[0];
    const int* ispad = (const int*)d_in[1];
    const float* wsv = (const float*)d_in[2];
    const float* cst = (const float*)d_in[3];
    const float* a1W = (const float*)d_in[4];
    const float* a1b = (const float*)d_in[5];
    const float* w1g = (const float*)d_in[6];
    const float* noise_c = (const float*)d_in[7];
    const float* nstr = (const float*)d_in[8];
    const float* bias1 = (const float*)d_in[9];
    const float* a2W = (const float*)d_in[10];
    const float* a2b = (const float*)d_in[11];
    const float* w2 = (const float*)d_in[12];
    const float* bias2 = (const float*)d_in[13];
    float* out = (float*)d_out;
    unsigned char* wsb = (unsigned char*)d_ws;

    k0_styles<<<1, 256, 0, stream>>>(wsv, a1W, a1b, a2W, a2b, w2, wsb);
    k0b_fold<<<256, 64, 0, stream>>>(w1g, (const float*)(wsb + WS_S1), (u16*)(wsb + WS_W1));
    k_cvt<<<4096, 256, 0, stream>>>(cst, (u16*)(wsb + WS_CONST));
    k1_conv<<<1024, 256, 0, stream>>>(neigh, ispad, noise_c, nstr, bias1, wsb, out);
    k2_img<<<8192, 256, 0, stream>>>(neigh, ispad, (const float*)(wsb + WS_W2F), bias2,
                                     out, out + XELEMS);
}

// Round 5
// 234.236 us; speedup vs baseline: 1.0122x; 1.0122x over previous
//
#include <hip/hip_runtime.h>

typedef unsigned short u16;
typedef __bf16 bf16x8 __attribute__((ext_vector_type(8)));
typedef float f32x4 __attribute__((ext_vector_type(4)));
typedef unsigned short u16x8 __attribute__((ext_vector_type(8)));

#define F_FACES 65536
#define N_FACES 131072
#define C_CH 128
// ws layout (bytes):
//   [0,256)        zeropage (zeros; masked-gather target)
//   [256,3328)     W2 folded fp32  [b][o][i]  (768 floats)
//   [3328,4352)    styles1 fp32    [b][i]     (256 floats)
//   [4352,5376)    styles2 fp32    [b][i]     (256 floats)
//   [5376,595200)  W1 folded bf16, FRAGMENT layout [b][k][chunk16][o128][j8]
//   [595200, +16777216) const bf16 copy [F][C]
#define WS_W2F 256
#define WS_S1 3328
#define WS_S2 4352
#define WS_W1 5376
#define WS_CONST 595200
#define XELEMS 16777216  // N_FACES*128

__device__ inline u16 f2bf(float f) {
    unsigned u = __builtin_bit_cast(unsigned, f);
    unsigned r = (u + 0x7fffu + ((u >> 16) & 1u)) >> 16;
    return (u16)r;
}

__device__ inline void gl_lds16(const void* g, void* l) {
    __builtin_amdgcn_global_load_lds(
        (const __attribute__((address_space(1))) void*)g,
        (__attribute__((address_space(3))) void*)l, 16, 0, 0);
}

// ---------------- kernel 0a: styles1+styles2, one wave per 512-dot ----------------
// grid 128 x 256: combo c = blockIdx*4+wave in [0,512): which=c>>8, b=(c>>7)&1, o=c&127
__global__ __launch_bounds__(256) void k0a_styles(
    const float* __restrict__ wsv, const float* __restrict__ a1W, const float* __restrict__ a1b,
    const float* __restrict__ a2W, const float* __restrict__ a2b, unsigned char* __restrict__ wsb)
{
    int wv = threadIdx.x >> 6, lane = threadIdx.x & 63;
    int c = blockIdx.x * 4 + wv;
    int which = c >> 8, rem = c & 255, b = rem >> 7, o = rem & 127;
    const float* W = (which ? a2W : a1W) + o * 512 + lane * 8;
    const float* x = wsv + (b * 2 + which) * 512 + lane * 8;
    float4 wa = *(const float4*)(W);
    float4 wb = *(const float4*)(W + 4);
    float4 xa = *(const float4*)(x);
    float4 xb = *(const float4*)(x + 4);
    float s = wa.x * xa.x + wa.y * xa.y + wa.z * xa.z + wa.w * xa.w
            + wb.x * xb.x + wb.y * xb.y + wb.z * xb.z + wb.w * xb.w;
#pragma unroll
    for (int d = 1; d < 64; d <<= 1) s += __shfl_xor(s, d);
    if (lane == 0) {
        const float g512 = 0.04419417382415922f;   // 1/sqrt(512)
        const float g128 = 0.08838834764831845f;   // 1/sqrt(128)
        float* wsf = (float*)wsb;
        if (which == 0) {
            wsf[WS_S1 / 4 + b * 128 + o] = s * g512 + a1b[o];
        } else {
            wsf[WS_S2 / 4 + b * 128 + o] = (s * g512 + a2b[o]) * g128;
        }
    }
}

// ---------------- kernel 0w: W2 fold + zeropage (tiny) ----------------
__global__ __launch_bounds__(256) void k0w_fold2(
    const float* __restrict__ w2, unsigned char* __restrict__ wsb)
{
    int t = threadIdx.x;
    float* wsf = (float*)wsb;
    if (t < 64) wsf[t] = 0.f;  // zeropage
#pragma unroll
    for (int r = 0; r < 3; ++r) {
        int id = t + r * 256;  // < 768
        int b2 = id / 384;
        int rem = id - b2 * 384;
        int o2 = rem >> 7;
        int i = rem & 127;
        wsf[WS_W2F / 4 + id] = w2[o2 * 128 + i] * wsf[WS_S2 / 4 + b2 * 128 + i];
    }
}

// ---------------- kernel 0b: demod + fold W1 (bf16 fragment layout) ----------------
__global__ __launch_bounds__(64) void k0b_fold(
    const float* __restrict__ w1g, const unsigned char* __restrict__ wsb, u16* __restrict__ w1out)
{
    int bo = blockIdx.x;
    int b = bo >> 7, o = bo & 127;
    int l = threadIdx.x;
    const float* s1 = (const float*)(wsb + WS_S1) + b * 128;
    float sum = 0.f;
    for (int e = l; e < 1152; e += 64) {
        int i = e / 9;
        float w = w1g[o * 1152 + e] * s1[i];
        sum += w * w;
    }
#pragma unroll
    for (int d = 1; d < 64; d <<= 1) sum += __shfl_xor(sum, d);
    float dm = rsqrtf(sum + 1e-8f);
    int i0 = l * 2;
    float sa = s1[i0] * dm, sb = s1[i0 + 1] * dm;
    int chunk = i0 >> 3, j = i0 & 7;
#pragma unroll
    for (int k = 0; k < 9; ++k) {
        float v0 = w1g[(o * 128 + i0) * 9 + k] * sa;
        float v1 = w1g[(o * 128 + i0 + 1) * 9 + k] * sb;
        unsigned pack = (unsigned)f2bf(v0) | ((unsigned)f2bf(v1) << 16);
        // fragment layout: [b][k][chunk][o][j]
        *(unsigned*)&w1out[(size_t)((((b * 9 + k) * 16 + chunk) * 128 + o) * 8 + j)] = pack;
    }
}

// ---------------- kernel 0c: const fp32 -> bf16 copy in ws ----------------
__global__ __launch_bounds__(256) void k_cvt(
    const float* __restrict__ src, u16* __restrict__ dst)
{
    int t = blockIdx.x * 256 + threadIdx.x;
    int base = t * 8;  // 4096 blocks * 256 thr * 8 = 8388608
    float4 a = *(const float4*)(src + base);
    float4 c = *(const float4*)(src + base + 4);
    u16x8 p;
    p[0] = f2bf(a.x); p[1] = f2bf(a.y); p[2] = f2bf(a.z); p[3] = f2bf(a.w);
    p[4] = f2bf(c.x); p[5] = f2bf(c.y); p[6] = f2bf(c.z); p[7] = f2bf(c.w);
    *(u16x8*)(dst + base) = p;
}

// ---------------- kernel 1: gathered GEMM conv1 + fused epilogue ----------------
// A staged via global_load_lds (32KB LDS, XOR-16 swizzle); B fragments loaded
// directly from L2-resident pre-folded ws (fragment layout) -> 4 blocks/CU.
__global__ __launch_bounds__(256, 4) void k1_conv(
    const int* __restrict__ neigh, const int* __restrict__ ispad,
    const float* __restrict__ noise_c, const float* __restrict__ nstr,
    const float* __restrict__ bias1, const unsigned char* __restrict__ wsb,
    float* __restrict__ out)
{
    __shared__ u16 As[128 * 128];  // 32KB, 128 faces x 128ch, 16B-chunk XOR swizzled

    int tid = threadIdx.x;
    int wv = tid >> 6, lane = tid & 63;
    int quad = lane >> 4, l15 = lane & 15;
    int f0 = blockIdx.x * 128;
    int b = f0 >> 16;
    const u16* cst = (const u16*)(wsb + WS_CONST);
    const u16* w1ws = (const u16*)(wsb + WS_W1) + (size_t)b * 147456;  // 9*16*128*8
    const char* zp = (const char*)wsb;

    f32x4 acc[4][4] = {};
    int wm = wv & 1, wn = wv >> 1;

    for (int k = 0; k < 9; ++k) {
        __syncthreads();
        // stage A (gather, masked -> zeropage), swizzled write
#pragma unroll
        for (int r = 0; r < 8; ++r) {
            int cid = ((wv * 8 + r) << 6) + lane;
            int row = cid >> 4;
            int slot = cid & 15;
            int nb = (f0 + row) * 9 + k;
            int idx = neigh[nb];
            bool valid = (ispad[nb] == 0) && ((unsigned)idx < 131072u);
            const char* src = valid ? ((const char*)(cst + ((size_t)(idx & 65535) << 7))) : zp;
            gl_lds16(src + ((slot ^ (row & 15)) << 4), (char*)As + ((wv * 8 + r) << 10));
        }
        __syncthreads();
#pragma unroll
        for (int s = 0; s < 4; ++s) {
            bf16x8 af[4], bfr[4];
#pragma unroll
            for (int mt = 0; mt < 4; ++mt) {
                int face = wm * 64 + mt * 16 + l15;
                int chunk = (s * 4 + quad) ^ (face & 15);
                af[mt] = *reinterpret_cast<const bf16x8*>(&As[face * 128 + chunk * 8]);
            }
            // B fragments direct from global (L2-hot, coalesced per quad)
            const u16* bp = w1ws + (((k * 16 + s * 4 + quad) * 128) + wn * 64 + l15) * 8;
#pragma unroll
            for (int nt = 0; nt < 4; ++nt)
                bfr[nt] = *reinterpret_cast<const bf16x8*>(bp + nt * 128);
#pragma unroll
            for (int mt = 0; mt < 4; ++mt)
#pragma unroll
                for (int nt = 0; nt < 4; ++nt)
                    acc[mt][nt] = __builtin_amdgcn_mfma_f32_16x16x32_bf16(
                        af[mt], bfr[nt], acc[mt][nt], 0, 0, 0);
        }
    }

    // epilogue: + noise + bias1, lrelu(0.2)*sqrt(2), clip +-256, fp32 store
    float ns = nstr[0];
    float b1v[4];
#pragma unroll
    for (int nt = 0; nt < 4; ++nt) b1v[nt] = bias1[wn * 64 + nt * 16 + l15];
#pragma unroll
    for (int mt = 0; mt < 4; ++mt) {
#pragma unroll
        for (int r = 0; r < 4; ++r) {
            int face = f0 + wm * 64 + mt * 16 + quad * 4 + r;
            float nz = noise_c[face & 65535] * ns;
#pragma unroll
            for (int nt = 0; nt < 4; ++nt) {
                float v = acc[mt][nt][r] + nz + b1v[nt];
                v = (v > 0.f) ? v : 0.2f * v;
                v *= 1.41421356f;
                v = fminf(fmaxf(v, -256.f), 256.f);
                out[(size_t)face * 128 + wn * 64 + nt * 16 + l15] = v;
            }
        }
    }
}

// ---------------- kernel 2: conv2 (k=1 gather) + bias + clip ----------------
__global__ __launch_bounds__(256) void k2_img(
    const int* __restrict__ neigh, const int* __restrict__ ispad,
    const float* __restrict__ w2f, const float* __restrict__ bias2,
    const float* __restrict__ xbuf, float* __restrict__ imgout)
{
    __shared__ float ws2[768];
    int tid = threadIdx.x;
    ws2[tid] = w2f[tid];
    ws2[tid + 256] = w2f[tid + 256];
    ws2[tid + 512] = w2f[tid + 512];
    __syncthreads();
    int wv = tid >> 6, lane = tid & 63;
    int g = lane >> 4, sub = lane & 15;
    int face = blockIdx.x * 16 + wv * 4 + g;
    int b = face >> 16;
    int idx = neigh[face * 9];
    bool valid = (ispad[face * 9] == 0) && ((unsigned)idx < 131072u);
    float a0 = 0.f, a1 = 0.f, a2 = 0.f;
    if (valid) {
        float4 d0 = *(const float4*)(xbuf + (size_t)idx * 128 + sub * 8);
        float4 d1 = *(const float4*)(xbuf + (size_t)idx * 128 + sub * 8 + 4);
        float f[8] = {d0.x, d0.y, d0.z, d0.w, d1.x, d1.y, d1.z, d1.w};
        const float* w0 = &ws2[(b * 3 + 0) * 128 + sub * 8];
        const float* w1 = &ws2[(b * 3 + 1) * 128 + sub * 8];
        const float* w2p = &ws2[(b * 3 + 2) * 128 + sub * 8];
#pragma unroll
        for (int j = 0; j < 8; ++j) {
            a0 += f[j] * w0[j];
            a1 += f[j] * w1[j];
            a2 += f[j] * w2p[j];
        }
    }
#pragma unroll
    for (int d = 1; d < 16; d <<= 1) {
        a0 += __shfl_xor(a0, d);
        a1 += __shfl_xor(a1, d);
        a2 += __shfl_xor(a2, d);
    }
    if (sub < 3) {
        float v = (sub == 0) ? a0 : (sub == 1) ? a1 : a2;
        v += bias2[sub];
        v = fminf(fmaxf(v, -256.f), 256.f);
        imgout[face * 3 + sub] = v;
    }
}

extern "C" void kernel_launch(void* const* d_in, const int* in_sizes, int n_in,
                              void* d_out, int out_size, void* d_ws, size_t ws_size,
                              hipStream_t stream) {
    const int* neigh = (const int*)d_in[0];
    const int* ispad = (const int*)d_in[1];
    const float* wsv = (const float*)d_in[2];
    const float* cst = (const float*)d_in[3];
    const float* a1W = (const float*)d_in[4];
    const float* a1b = (const float*)d_in[5];
    const float* w1g = (const float*)d_in[6];
    const float* noise_c = (const float*)d_in[7];
    const float* nstr = (const float*)d_in[8];
    const float* bias1 = (const float*)d_in[9];
    const float* a2W = (const float*)d_in[10];
    const float* a2b = (const float*)d_in[11];
    const float* w2 = (const float*)d_in[12];
    const float* bias2 = (const float*)d_in[13];
    float* out = (float*)d_out;
    unsigned char* wsb = (unsigned char*)d_ws;

    k0a_styles<<<128, 256, 0, stream>>>(wsv, a1W, a1b, a2W, a2b, wsb);
    k0w_fold2<<<1, 256, 0, stream>>>(w2, wsb);
    k0b_fold<<<256, 64, 0, stream>>>(w1g, wsb, (u16*)(wsb + WS_W1));
    k_cvt<<<4096, 256, 0, stream>>>(cst, (u16*)(wsb + WS_CONST));
    k1_conv<<<1024, 256, 0, stream>>>(neigh, ispad, noise_c, nstr, bias1, wsb, out);
    k2_img<<<8192, 256, 0, stream>>>(neigh, ispad, (const float*)(wsb + WS_W2F), bias2,
                                     out, out + XELEMS);
}